// Round 1
// baseline (45854.138 us; speedup 1.0000x reference)
//
#include <hip/hip_runtime.h>
#include <hip/hip_cooperative_groups.h>

namespace cg = cooperative_groups;

#define T_STEPS 512
#define BATCH 64
#define IDIM 256
#define HDIM 2048

// Transpose x [T,B,I] -> xT [T,I,B] and initial_state [B,H] -> SA [H,B].
// 64x64 tiles via LDS, fully coalesced both sides.
__global__ __launch_bounds__(256) void prep_kernel(
    const float* __restrict__ x, const float* __restrict__ s0,
    float* __restrict__ xT, float* __restrict__ SA) {
  __shared__ float tile[64][65];
  const int bid = blockIdx.x;
  const int c0 = threadIdx.x & 63;
  const int g = threadIdx.x >> 6;  // 0..3

  const float* srcbase;
  float* dstbase;
  int sstride;
  if (bid < 2048) {               // x tiles: T * (I/64) = 512*4
    const int t = bid >> 2;
    const int kb = (bid & 3) * 64;
    srcbase = x + t * (BATCH * IDIM) + kb;   // element (r,c) = [t][r][kb+c]
    sstride = IDIM;
    dstbase = xT + t * (IDIM * BATCH) + kb * 64;  // element (c,r) = [t][kb+c][r]
  } else {                        // initial_state tiles: H/64 = 32
    const int i = bid - 2048;
    const int hb = i * 64;
    srcbase = s0 + hb;            // element (r,c) = s0[r][hb+c], stride H
    sstride = HDIM;
    dstbase = SA + hb * 64;       // element (c,r) = SA[hb+c][r]
  }

#pragma unroll
  for (int rr = 0; rr < 16; ++rr) {
    const int r = rr * 4 + g;
    tile[r][c0] = srcbase[r * sstride + c0];
  }
  __syncthreads();
#pragma unroll
  for (int cc = 0; cc < 16; ++cc) {
    const int c = cc * 4 + g;
    dstbase[c * 64 + c0] = tile[c0][c];  // dst(c, r=c0) = tile[r=c0][c]
  }
}

// Persistent cooperative reservoir kernel.
// Grid: 256 blocks x 512 threads. Block owns j-tile of 8 columns.
// 8 waves K-split the 2304-long dot (256 x-part + 2048 s-part).
// lane = b (64 = wave size): vector operand coalesced, W operand wave-uniform.
__global__ __launch_bounds__(512) void reservoir_kernel(
    const float* __restrict__ xT, const float* __restrict__ Win,
    const float* __restrict__ What, float* __restrict__ SA,
    float* __restrict__ SB, float* __restrict__ out) {
  cg::grid_group grid = cg::this_grid();
  __shared__ float lds[8 * 8 * 64];  // [wave][jj][b], 16 KiB
  const int jt = blockIdx.x * 8;
  const int w = threadIdx.x >> 6;  // 0..7
  const int b = threadIdx.x & 63;

  for (int t = 0; t < T_STEPS; ++t) {
    const float* __restrict__ Scur = (t & 1) ? SB : SA;
    float* __restrict__ Snxt = (t & 1) ? SA : SB;

    float acc[8];
#pragma unroll
    for (int jj = 0; jj < 8; ++jj) acc[jj] = 0.0f;

    // ---- x part: K-chunk of 32 per wave ----
    const float* xTt = xT + t * (IDIM * BATCH);
    {
      const int kbeg = w * 32;
#pragma unroll
      for (int k = kbeg; k < kbeg + 32; k += 8) {
        float xv[8];
#pragma unroll
        for (int u = 0; u < 8; ++u) xv[u] = xTt[(k + u) * 64 + b];
#pragma unroll
        for (int jj = 0; jj < 8; ++jj) {
          const float* wr = Win + (jt + jj) * IDIM + k;  // wave-uniform -> s_load
#pragma unroll
          for (int u = 0; u < 8; ++u) acc[jj] = fmaf(xv[u], wr[u], acc[jj]);
        }
      }
    }

    // ---- s part: K-chunk of 256 per wave ----
    {
      const int kbeg = w * 256;
      for (int k = kbeg; k < kbeg + 256; k += 8) {
        float sv[8];
#pragma unroll
        for (int u = 0; u < 8; ++u) sv[u] = Scur[(k + u) * 64 + b];
#pragma unroll
        for (int jj = 0; jj < 8; ++jj) {
          const float* wr = What + (jt + jj) * HDIM + k;  // wave-uniform -> s_load
#pragma unroll
          for (int u = 0; u < 8; ++u) acc[jj] = fmaf(sv[u], wr[u], acc[jj]);
        }
      }
    }

    // ---- cross-wave reduce + activation + leaky update ----
#pragma unroll
    for (int jj = 0; jj < 8; ++jj) lds[(w * 8 + jj) * 64 + b] = acc[jj];
    __syncthreads();
    {
      const int jj = w;   // 0..7 with 512 threads: each thread owns one (jj,b)
      float s = 0.0f;
#pragma unroll
      for (int ww = 0; ww < 8; ++ww) s += lds[(ww * 8 + jj) * 64 + b];
      const float h = tanhf(s);
      const int j = jt + jj;
      const float sold = Scur[j * 64 + b];
      const float snew = 0.5f * (sold + h);
      Snxt[j * 64 + b] = snew;
      out[(size_t)t * (BATCH * HDIM) + (size_t)b * HDIM + j] = snew;
    }
    grid.sync();  // next step reads the full new state written by all blocks
  }
}

extern "C" void kernel_launch(void* const* d_in, const int* in_sizes, int n_in,
                              void* d_out, int out_size, void* d_ws, size_t ws_size,
                              hipStream_t stream) {
  const float* x = (const float*)d_in[0];      // [512,64,256]
  const float* s0 = (const float*)d_in[1];     // [64,2048]
  const float* Win = (const float*)d_in[2];    // [2048,256]
  const float* What = (const float*)d_in[3];   // [2048,2048]
  float* out = (float*)d_out;                  // [512,64,2048]

  float* ws = (float*)d_ws;
  float* xT = ws;                                         // 8388608 floats (33.5 MB)
  float* SA = ws + (size_t)T_STEPS * IDIM * BATCH;        // 131072 floats
  float* SB = SA + HDIM * BATCH;                          // 131072 floats

  prep_kernel<<<2080, 256, 0, stream>>>(x, s0, xT, SA);

  void* args[] = {(void*)&xT, (void*)&Win, (void*)&What,
                  (void*)&SA, (void*)&SB, (void*)&out};
  hipLaunchCooperativeKernel((const void*)reservoir_kernel, dim3(256), dim3(512),
                             args, 0, stream);
}

// Round 2
// 21073.708 us; speedup vs baseline: 2.1759x; 2.1759x over previous
//
#include <hip/hip_runtime.h>
#include <hip/hip_cooperative_groups.h>

namespace cg = cooperative_groups;

typedef __attribute__((ext_vector_type(8))) short short8;
typedef __attribute__((ext_vector_type(4))) float floatx4;

#define TT 512
#define BB 64
#define II 256
#define HH 2048

#define MFMA(a, b, c) __builtin_amdgcn_mfma_f32_16x16x32_bf16(a, b, c, 0, 0, 0)

__device__ __forceinline__ short f2bf(float f) {
  unsigned u = __builtin_bit_cast(unsigned, f);
  u = (u + 0x7fffu + ((u >> 16) & 1u)) >> 16;
  return (short)u;
}
__device__ __forceinline__ float bf2f(short s) {
  unsigned u = ((unsigned)(unsigned short)s) << 16;
  return __builtin_bit_cast(float, u);
}

// ---- initial state -> bf16 hi/lo buffers ([b][h] layout) ----
__global__ __launch_bounds__(256) void prep_state(const float* __restrict__ s0,
                                                  short* __restrict__ Shi,
                                                  short* __restrict__ Slo) {
  int i = blockIdx.x * 256 + threadIdx.x;  // 131072 total
  float f = s0[i];
  short h = f2bf(f);
  Shi[i] = h;
  Slo[i] = f2bf(f - bf2f(h));
}

// ---- u = X @ Win^T, X: [32768][256] (= x[t][b][i]), Win: [2048][256],
//      U: [32768][2048] (= d_out, row (t*64+b), col h). fp32 in/out,
//      bf16 hi/lo split 3-product MFMA internally. ----
__global__ __launch_bounds__(256) void ugemm(const float* __restrict__ X,
                                             const float* __restrict__ Win,
                                             float* __restrict__ U) {
  const int w = threadIdx.x >> 6;
  const int L = threadIdx.x & 63;
  const int lm = L & 15, lq = L >> 4;
  const int m0 = blockIdx.x * 128 + (w >> 1) * 64;  // gridDim.x = 256
  const int n0 = blockIdx.y * 64 + (w & 1) * 32;    // gridDim.y = 32

  short8 Bhi[2][8], Blo[2][8];
#pragma unroll
  for (int nt = 0; nt < 2; ++nt)
#pragma unroll
    for (int kt = 0; kt < 8; ++kt) {
      const float* p = Win + (n0 + nt * 16 + lm) * II + kt * 32 + lq * 8;
      short8 hi, lo;
#pragma unroll
      for (int j = 0; j < 8; ++j) {
        float f = p[j];
        short h = f2bf(f);
        hi[j] = h;
        lo[j] = f2bf(f - bf2f(h));
      }
      Bhi[nt][kt] = hi;
      Blo[nt][kt] = lo;
    }

#pragma unroll 1
  for (int mt = 0; mt < 4; ++mt) {
    short8 Ahi[8], Alo[8];
    const int r = m0 + mt * 16 + lm;
#pragma unroll
    for (int kt = 0; kt < 8; ++kt) {
      const float* p = X + (size_t)r * II + kt * 32 + lq * 8;
      short8 hi, lo;
#pragma unroll
      for (int j = 0; j < 8; ++j) {
        float f = p[j];
        short h = f2bf(f);
        hi[j] = h;
        lo[j] = f2bf(f - bf2f(h));
      }
      Ahi[kt] = hi;
      Alo[kt] = lo;
    }
#pragma unroll
    for (int nt = 0; nt < 2; ++nt) {
      floatx4 acc = {0.f, 0.f, 0.f, 0.f};
#pragma unroll
      for (int kt = 0; kt < 8; ++kt) {
        acc = MFMA(Ahi[kt], Bhi[nt][kt], acc);
        acc = MFMA(Ahi[kt], Blo[nt][kt], acc);
        acc = MFMA(Alo[kt], Bhi[nt][kt], acc);
      }
      // C layout: col = lane&15, row = (lane>>4)*4 + reg
#pragma unroll
      for (int rr = 0; rr < 4; ++rr) {
        int row = m0 + mt * 16 + lq * 4 + rr;
        int col = n0 + nt * 16 + lm;
        U[(size_t)row * HH + col] = acc[rr];
      }
    }
  }
}

// ---- persistent recurrent kernel ----
// 256 blocks x 512 thr. block = (n-slice of 16 cols jt, m-half mhalf).
// 8 waves k-split K=2048 (256 each); W_hat fragments register-resident
// (bf16 hi/lo, loaded once from fp32). One grid.sync per step.
__global__ __launch_bounds__(512, 2) void reservoir(
    const float* __restrict__ What, const float* __restrict__ s0,
    short* __restrict__ SAh, short* __restrict__ SAl,
    short* __restrict__ SBh, short* __restrict__ SBl,
    float* __restrict__ out) {
  cg::grid_group grid = cg::this_grid();
  __shared__ float red[8][32][17];  // [wave][m-row][h-col], padded

  const int jt = (blockIdx.x >> 1) << 4;  // 128 n-groups * 16
  const int mhalf = blockIdx.x & 1;
  const int w = threadIdx.x >> 6;
  const int L = threadIdx.x & 63;
  const int lm = L & 15, lq = L >> 4;
  const int kw = w << 8;  // wave k-base (256 per wave)

  // Load W_hat B-fragments once: B[n=lane&15][k=(lane>>4)*8 + j]
  short8 Whi[8], Wlo[8];
#pragma unroll
  for (int kt = 0; kt < 8; ++kt) {
    const float* p = What + (size_t)(jt + lm) * HH + kw + kt * 32 + lq * 8;
    short8 hi, lo;
#pragma unroll
    for (int j = 0; j < 8; ++j) {
      float f = p[j];
      short h = f2bf(f);
      hi[j] = h;
      lo[j] = f2bf(f - bf2f(h));
    }
    Whi[kt] = hi;
    Wlo[kt] = lo;
  }

  // Epilogue element ownership: 512 threads -> 32 m-rows x 16 h-cols
  const int tid = threadIdx.x;
  const int eb = tid >> 4, eh = tid & 15;
  const int gb = mhalf * 32 + eb;
  const int gh = jt + eh;
  float s_prev = s0[gb * HH + gh];  // exact fp32 state, register-carried

  const int b0 = mhalf * 32 + lm;  // A-fragment m row (mt=0; mt=1 is +16)

  for (int t = 0; t < TT; ++t) {
    const short* __restrict__ Sh = (t & 1) ? SBh : SAh;
    const short* __restrict__ Sl = (t & 1) ? SBl : SAl;
    short* __restrict__ Nh = (t & 1) ? SAh : SBh;
    short* __restrict__ Nl = (t & 1) ? SAl : SBl;

    float u_val = out[(size_t)t * (BB * HH) + gb * HH + gh];  // u written by ugemm

    floatx4 acc0 = {0.f, 0.f, 0.f, 0.f};
    floatx4 acc1 = {0.f, 0.f, 0.f, 0.f};
#pragma unroll
    for (int kt = 0; kt < 8; ++kt) {
      const int k0 = kw + kt * 32 + lq * 8;
      short8 a0h = *(const short8*)(Sh + b0 * HH + k0);
      short8 a0l = *(const short8*)(Sl + b0 * HH + k0);
      short8 a1h = *(const short8*)(Sh + (b0 + 16) * HH + k0);
      short8 a1l = *(const short8*)(Sl + (b0 + 16) * HH + k0);
      acc0 = MFMA(a0h, Whi[kt], acc0);
      acc0 = MFMA(a0h, Wlo[kt], acc0);
      acc0 = MFMA(a0l, Whi[kt], acc0);
      acc1 = MFMA(a1h, Whi[kt], acc1);
      acc1 = MFMA(a1h, Wlo[kt], acc1);
      acc1 = MFMA(a1l, Whi[kt], acc1);
    }

    // dump partials: C layout col=lane&15 (h), row=(lane>>4)*4+reg (m)
#pragma unroll
    for (int r = 0; r < 4; ++r) {
      red[w][lq * 4 + r][lm] = acc0[r];
      red[w][16 + lq * 4 + r][lm] = acc1[r];
    }
    __syncthreads();

    float z = u_val;
#pragma unroll
    for (int ww = 0; ww < 8; ++ww) z += red[ww][eb][eh];
    float hv = tanhf(z);
    float snew = 0.5f * (s_prev + hv);
    s_prev = snew;
    out[(size_t)t * (BB * HH) + gb * HH + gh] = snew;
    short shi = f2bf(snew);
    Nh[gb * HH + gh] = shi;
    Nl[gb * HH + gh] = f2bf(snew - bf2f(shi));

    grid.sync();  // release new state to all XCDs
  }
}

extern "C" void kernel_launch(void* const* d_in, const int* in_sizes, int n_in,
                              void* d_out, int out_size, void* d_ws, size_t ws_size,
                              hipStream_t stream) {
  const float* x = (const float*)d_in[0];     // [512,64,256]
  const float* s0 = (const float*)d_in[1];    // [64,2048]
  const float* Win = (const float*)d_in[2];   // [2048,256]
  const float* What = (const float*)d_in[3];  // [2048,2048]
  float* out = (float*)d_out;                 // [512,64,2048]

  short* SAh = (short*)d_ws;                  // 4 x 131072 bf16 = 1 MB total
  short* SAl = SAh + BB * HH;
  short* SBh = SAl + BB * HH;
  short* SBl = SBh + BB * HH;

  prep_state<<<512, 256, 0, stream>>>(s0, SAh, SAl);
  ugemm<<<dim3(256, 32), 256, 0, stream>>>(x, Win, out);

  void* args[] = {(void*)&What, (void*)&s0, (void*)&SAh, (void*)&SAl,
                  (void*)&SBh, (void*)&SBl, (void*)&out};
  hipLaunchCooperativeKernel((const void*)reservoir, dim3(256), dim3(512),
                             args, 0, stream);
}

// Round 3
// 7830.158 us; speedup vs baseline: 5.8561x; 2.6914x over previous
//
#include <hip/hip_runtime.h>

typedef __attribute__((ext_vector_type(8))) short short8;
typedef __attribute__((ext_vector_type(4))) float floatx4;

#define TT 512
#define BB 64
#define II 256
#define HH 2048

#define MFMA(a, b, c) __builtin_amdgcn_mfma_f32_16x16x32_bf16(a, b, c, 0, 0, 0)

__device__ __forceinline__ short f2bf(float f) {
  unsigned u = __builtin_bit_cast(unsigned, f);
  u = (u + 0x7fffu + ((u >> 16) & 1u)) >> 16;
  return (short)u;
}
__device__ __forceinline__ float bf2f(short s) {
  unsigned u = ((unsigned)(unsigned short)s) << 16;
  return __builtin_bit_cast(float, u);
}

// ---- pack W_hat [2048][2048] fp32 -> MFMA-B-fragment-ordered bf16 hi/lo ----
// grid: 8192 blocks (ntile 0..127, kblock 0..63) x 64 threads.
// PW[(ntile*64 + kblock)*64 + lane] = short8 of W[ntile*16 + (lane&15)][kblock*32 + (lane>>4)*8 + j]
__global__ __launch_bounds__(64) void pack_what(const float* __restrict__ What,
                                                short8* __restrict__ PWhi,
                                                short8* __restrict__ PWlo) {
  const int ntile = blockIdx.x >> 6;
  const int kb = blockIdx.x & 63;
  const int L = threadIdx.x;
  const int lm = L & 15, lq = L >> 4;
  const float* p = What + (size_t)(ntile * 16 + lm) * HH + kb * 32 + lq * 8;
  short8 hi, lo;
#pragma unroll
  for (int j = 0; j < 8; ++j) {
    float f = p[j];
    short h = f2bf(f);
    hi[j] = h;
    lo[j] = f2bf(f - bf2f(h));
  }
  const size_t o = (size_t)blockIdx.x * 64 + L;
  PWhi[o] = hi;
  PWlo[o] = lo;
}

// ---- initial state -> bf16 hi/lo [64][2048] ----
__global__ __launch_bounds__(256) void prep_state(const float* __restrict__ s0,
                                                  short* __restrict__ Shi,
                                                  short* __restrict__ Slo) {
  int i = blockIdx.x * 256 + threadIdx.x;  // 131072 total
  float f = s0[i];
  short h = f2bf(f);
  Shi[i] = h;
  Slo[i] = f2bf(f - bf2f(h));
}

// ---- u = X @ Win^T into d_out (round-2 kernel, verified) ----
__global__ __launch_bounds__(256) void ugemm(const float* __restrict__ X,
                                             const float* __restrict__ Win,
                                             float* __restrict__ U) {
  const int w = threadIdx.x >> 6;
  const int L = threadIdx.x & 63;
  const int lm = L & 15, lq = L >> 4;
  const int m0 = blockIdx.x * 128 + (w >> 1) * 64;
  const int n0 = blockIdx.y * 64 + (w & 1) * 32;

  short8 Bhi[2][8], Blo[2][8];
#pragma unroll
  for (int nt = 0; nt < 2; ++nt)
#pragma unroll
    for (int kt = 0; kt < 8; ++kt) {
      const float* p = Win + (n0 + nt * 16 + lm) * II + kt * 32 + lq * 8;
      short8 hi, lo;
#pragma unroll
      for (int j = 0; j < 8; ++j) {
        float f = p[j];
        short h = f2bf(f);
        hi[j] = h;
        lo[j] = f2bf(f - bf2f(h));
      }
      Bhi[nt][kt] = hi;
      Blo[nt][kt] = lo;
    }

#pragma unroll 1
  for (int mt = 0; mt < 4; ++mt) {
    short8 Ahi[8], Alo[8];
    const int r = m0 + mt * 16 + lm;
#pragma unroll
    for (int kt = 0; kt < 8; ++kt) {
      const float* p = X + (size_t)r * II + kt * 32 + lq * 8;
      short8 hi, lo;
#pragma unroll
      for (int j = 0; j < 8; ++j) {
        float f = p[j];
        short h = f2bf(f);
        hi[j] = h;
        lo[j] = f2bf(f - bf2f(h));
      }
      Ahi[kt] = hi;
      Alo[kt] = lo;
    }
#pragma unroll
    for (int nt = 0; nt < 2; ++nt) {
      floatx4 acc = {0.f, 0.f, 0.f, 0.f};
#pragma unroll
      for (int kt = 0; kt < 8; ++kt) {
        acc = MFMA(Ahi[kt], Bhi[nt][kt], acc);
        acc = MFMA(Ahi[kt], Blo[nt][kt], acc);
        acc = MFMA(Alo[kt], Bhi[nt][kt], acc);
      }
#pragma unroll
      for (int rr = 0; rr < 4; ++rr) {
        int row = m0 + mt * 16 + lq * 4 + rr;
        int col = n0 + nt * 16 + lm;
        U[(size_t)row * HH + col] = acc[rr];
      }
    }
  }
}

// ---- one recurrence step ----
// grid 256 blocks x 256 thr. block = (mhalf: 32 b-rows, ntile: 16 h-cols).
// 4 waves k-split K=2048 (512 each). W streamed from packed L2-resident frags.
__global__ __launch_bounds__(256) void step_kernel(
    const short8* __restrict__ PWhi, const short8* __restrict__ PWlo,
    const short* __restrict__ Sh, const short* __restrict__ Sl,
    short* __restrict__ Nh, short* __restrict__ Nl,
    float* __restrict__ out_t) {
  __shared__ float red[4][32][17];
  const int w = threadIdx.x >> 6;
  const int L = threadIdx.x & 63;
  const int lm = L & 15, lq = L >> 4;
  const int mhalf = blockIdx.x & 1;
  const int ntile = blockIdx.x >> 1;  // 0..127
  const int mbase = mhalf * 32;
  const int kw = w * 512;  // wave k-base

  floatx4 acc0 = {0.f, 0.f, 0.f, 0.f};
  floatx4 acc1 = {0.f, 0.f, 0.f, 0.f};
  const size_t wbase = ((size_t)ntile * 64 + (kw >> 5)) * 64 + L;
#pragma unroll
  for (int kt = 0; kt < 16; ++kt) {
    short8 bh = PWhi[wbase + (size_t)kt * 64];
    short8 bl = PWlo[wbase + (size_t)kt * 64];
    const int k0 = kw + kt * 32 + lq * 8;
    short8 a0h = *(const short8*)(Sh + (mbase + lm) * HH + k0);
    short8 a0l = *(const short8*)(Sl + (mbase + lm) * HH + k0);
    short8 a1h = *(const short8*)(Sh + (mbase + 16 + lm) * HH + k0);
    short8 a1l = *(const short8*)(Sl + (mbase + 16 + lm) * HH + k0);
    acc0 = MFMA(a0h, bh, acc0);
    acc0 = MFMA(a0h, bl, acc0);
    acc0 = MFMA(a0l, bh, acc0);
    acc1 = MFMA(a1h, bh, acc1);
    acc1 = MFMA(a1h, bl, acc1);
    acc1 = MFMA(a1l, bh, acc1);
  }

  // C layout: col = lane&15 (n), row = (lane>>4)*4 + reg (m)
#pragma unroll
  for (int r = 0; r < 4; ++r) {
    red[w][lq * 4 + r][lm] = acc0[r];
    red[w][16 + lq * 4 + r][lm] = acc1[r];
  }
  __syncthreads();

#pragma unroll
  for (int p = 0; p < 2; ++p) {
    const int e = threadIdx.x + p * 256;
    const int row = e >> 4, col = e & 15;
    const int gb = mbase + row;
    const int gh = ntile * 16 + col;
    const int idx = gb * HH + gh;
    float z = out_t[idx];  // u_t (written by ugemm)
#pragma unroll
    for (int ww = 0; ww < 4; ++ww) z += red[ww][row][col];
    const float sp = bf2f(Sh[idx]) + bf2f(Sl[idx]);
    const float hv = tanhf(z);
    const float sn = 0.5f * (sp + hv);
    out_t[idx] = sn;
    const short shi = f2bf(sn);
    Nh[idx] = shi;
    Nl[idx] = f2bf(sn - bf2f(shi));
  }
}

extern "C" void kernel_launch(void* const* d_in, const int* in_sizes, int n_in,
                              void* d_out, int out_size, void* d_ws, size_t ws_size,
                              hipStream_t stream) {
  const float* x = (const float*)d_in[0];     // [512,64,256]
  const float* s0 = (const float*)d_in[1];    // [64,2048]
  const float* Win = (const float*)d_in[2];   // [2048,256]
  const float* What = (const float*)d_in[3];  // [2048,2048]
  float* out = (float*)d_out;                 // [512,64,2048]

  short8* PWhi = (short8*)d_ws;                          // 8 MB
  short8* PWlo = PWhi + (size_t)HH * HH / 8;             // 8 MB
  short* SAh = (short*)(PWlo + (size_t)HH * HH / 8);     // 256 KB each
  short* SAl = SAh + BB * HH;
  short* SBh = SAl + BB * HH;
  short* SBl = SBh + BB * HH;

  pack_what<<<8192, 64, 0, stream>>>(What, PWhi, PWlo);
  prep_state<<<512, 256, 0, stream>>>(s0, SAh, SAl);
  ugemm<<<dim3(256, 32), 256, 0, stream>>>(x, Win, out);

  for (int t = 0; t < TT; ++t) {
    const short* curH = (t & 1) ? SBh : SAh;
    const short* curL = (t & 1) ? SBl : SAl;
    short* nxtH = (t & 1) ? SAh : SBh;
    short* nxtL = (t & 1) ? SAl : SBl;
    step_kernel<<<256, 256, 0, stream>>>(PWhi, PWlo, curH, curL, nxtH, nxtL,
                                         out + (size_t)t * BB * HH);
  }
}